// Round 8
// baseline (178.353 us; speedup 1.0000x reference)
//
#include <hip/hip_runtime.h>
#include <stdint.h>

#define HWPOS 1024
#define CCH   256
#define RROWS 128   // 2B
#define EPSF  1.1920928955078125e-07f

typedef __attribute__((ext_vector_type(4))) float float4v;

// 64 partial-sum slots (64B padded) for gram's spread atomics; zeroed by
// k_transpose block (0,0) (stream order + kernel boundary => race-free).
__device__ float g_acc[64 * 16];

__device__ __forceinline__ uint32_t pk4_fp8(float a, float b, float c, float d) {
  int v = 0;
  v = __builtin_amdgcn_cvt_pk_fp8_f32(a, b, v, false);  // bytes 0,1
  v = __builtin_amdgcn_cvt_pk_fp8_f32(c, d, v, true);   // bytes 2,3
  return (uint32_t)v;
}

// ws layout v14 (fp8): addr(r, s, hw) = (r*4 + (s>>2))*65536 + hw*64 + (s&3)*16
// with slot s = dd ^ (r & 15) (dd = c-chunk, 16 c each). Identity used:
//   s>>2 = q ^ ((r>>2)&3),  s&3 = k ^ (r&3)   for dd = 4q + k.
// => producer block (r,q) owns ONE contiguous 64KB region; k_gram's LDS image
// (Fs) is byte-identical to all prior versions -> MFMA/softmax algebra kept.

// ---------------------------------------------------------------------------
// Kernel 1 (v14, fp8): transpose [B,C,H,W] f32 -> ws fp8-e4m3.
// v14 change: DRAM-ROW-DENSE reads. Block = 1 r x 64 c x 1024 hw (512 thr):
// reads 256 KB fully contiguous per block (previous variants used only a
// 128-512B hw-window per 4KB row -> row thrash, stuck at 1.8 TB/s; the
// harness's own fillBuffer proves 6.6 TB/s is reachable).
// Per sub-tile k (16 c x 1024 hw = 64 KB f32):
//   load 8 float4/thread (contiguous) -> LDS T[c][hw] (row store, col read,
//   both <=2-way conflicts) -> cvt to fp8 chunk (16 c) -> one 16B store per
//   hw into the block's contiguous 64KB ws region (slot sl3 = k ^ (r&3)).
// Grid (128 r, 4 q) = 512 blocks; LDS 64 KB -> 2 blocks/CU.
// ---------------------------------------------------------------------------
__global__ __launch_bounds__(512, 2) void k_transpose(const float* __restrict__ inp,
                                                      const float* __restrict__ tgt,
                                                      unsigned char* __restrict__ wsF) {
  __shared__ float T[16 * 1024];    // 64 KB: [c_l 0..15][hw 0..1023]
  const int t = threadIdx.x;
  const int r = blockIdx.x;         // row 0..127
  const int q = blockIdx.y;         // c-quarter 0..3 (64 c)
  if (r == 0 && q == 0 && t < 64) g_acc[t * 16] = 0.0f;
  const float* src = (r < 64) ? (inp + (size_t)r * CCH * HWPOS)
                              : (tgt + (size_t)(r - 64) * CCH * HWPOS);
  const int c_l = t >> 5;           // 0..15 (c within sub-tile)
  const int l32 = t & 31;
  const int qs  = q ^ ((r >> 2) & 3);
  const size_t regbase = (size_t)(r * 4 + qs) * 65536;
#pragma unroll
  for (int k = 0; k < 4; ++k) {
    const int dd = q * 4 + k;       // global c-chunk 0..15
    const float* gp = src + (size_t)(dd * 16 + c_l) * HWPOS + l32 * 4;
    float4 v[8];
#pragma unroll
    for (int j = 0; j < 8; ++j) v[j] = *(const float4*)(gp + j * 128);
#pragma unroll
    for (int j = 0; j < 8; ++j)
      *(float4*)&T[c_l * 1024 + l32 * 4 + j * 128] = v[j];
    __syncthreads();
    const int sl3 = k ^ (r & 3);    // slot within 64B group (block-uniform)
#pragma unroll
    for (int h2 = 0; h2 < 2; ++h2) {
      const int hw = t + h2 * 512;
      float x[16];
#pragma unroll
      for (int c = 0; c < 16; ++c) x[c] = T[c * 1024 + hw];  // col read: free
      uint4 o;
      o.x = pk4_fp8(x[0],  x[1],  x[2],  x[3]);
      o.y = pk4_fp8(x[4],  x[5],  x[6],  x[7]);
      o.z = pk4_fp8(x[8],  x[9],  x[10], x[11]);
      o.w = pk4_fp8(x[12], x[13], x[14], x[15]);
      *(uint4*)(wsF + regbase + (size_t)hw * 64 + sl3 * 16) = o;
    }
    __syncthreads();
  }
}

// ---------------------------------------------------------------------------
// Kernel 2 (v8, fp8): one block per hw; whole 32KB fp8 image in one LDS
// buffer; 8 waves x mfma_f32_16x16x32_fp8_fp8; fused masked log-softmax +
// positive-pair extraction; spread atomics into g_acc. v8 change: staging
// address follows ws v14 (chunk ch=(r,s): (r*4+(s>>2))*65536 + hw*64 +
// (s&3)*16 -> per wave 16 x 64B segments). Fs contents byte-identical.
// ---------------------------------------------------------------------------
__global__ __launch_bounds__(512, 4) void k_gram(const unsigned char* __restrict__ wsF) {
  __shared__ unsigned char Fs[32768];   // full fp8 image, swizzled
  __shared__ float sInv[RROWS];
  __shared__ float wred[8];
  const int t  = threadIdx.x;
  const int hw = blockIdx.x;
  const int lane = t & 63;
  const int w    = t >> 6;        // wave id 0..7 = row-tile
  const int lid  = lane & 15;
  const int quad = lane >> 4;
  float4v acc[8];
#pragma unroll
  for (int ni = 0; ni < 8; ++ni) acc[ni] = (float4v){0.f, 0.f, 0.f, 0.f};
#pragma unroll
  for (int it = 0; it < 4; ++it) {
    const int ch = it * 512 + t;                    // Fs chunk index 0..2047
    const int rr = ch >> 4;                         // r page
    const int ss = ch & 15;                         // slot within row
    const size_t goff = (size_t)((rr << 2) + (ss >> 2)) * 65536
                      + (size_t)hw * 64 + (size_t)(ss & 3) * 16;
    __builtin_amdgcn_global_load_lds(
        (const __attribute__((address_space(1))) unsigned int*)(wsF + goff),
        (__attribute__((address_space(3))) unsigned int*)(Fs + (size_t)ch * 16),
        16, 0, 0);
  }
  __syncthreads();
  const int rowA = (w << 4) | lid;
#pragma unroll
  for (int ks = 0; ks < 8; ++ks) {
    const int d    = 2 * ks + (quad >> 1);      // data chunk for this frag
    const int off  = ((d ^ lid) << 4) + (quad & 1) * 8;  // swizzled byte off
    long a = *(const long*)&Fs[rowA * 256 + off];
#pragma unroll
    for (int ni = 0; ni < 8; ++ni) {
      long b = *(const long*)&Fs[(((ni << 4) | lid)) * 256 + off];
      acc[ni] = __builtin_amdgcn_mfma_f32_16x16x32_fp8_fp8(a, b, acc[ni], 0, 0, 0);
    }
  }
  // diagonal extract (no dynamic indexing): tile w (uniform), elem lid&3
  {
    float diagv = 0.f;
#pragma unroll
    for (int ni = 0; ni < 8; ++ni) {
      if (ni == w) {
#pragma unroll
        for (int e = 0; e < 4; ++e)
          if (e == (lid & 3)) diagv = acc[ni][e];
      }
    }
    if ((lid >> 2) == quad) {
      sInv[(w << 4) | lid] = 1.0f / fmaxf(sqrtf(diagv), EPSF);
    }
  }
  __syncthreads();
  float invj[8];
#pragma unroll
  for (int ni = 0; ni < 8; ++ni) invj[ni] = sInv[(ni << 4) | lid];
  const int tj = (w + 4) & 7;     // partner col-tile (wave-uniform)
  float lacc = 0.f;
#pragma unroll
  for (int reg = 0; reg < 4; ++reg) {
    const int rloc = quad * 4 + reg;           // local row in tile
    const int rg   = (w << 4) | rloc;          // global row 0..127
    const float invi = sInv[rg];
    float v[8];
#pragma unroll
    for (int ni = 0; ni < 8; ++ni) v[ni] = 2.0f * acc[ni][reg] * invi * invj[ni];
#pragma unroll
    for (int ni = 0; ni < 8; ++ni)
      if (ni == w && lid == rloc) v[ni] = -3.0e38f;   // mask diagonal
    float mx = v[0];
#pragma unroll
    for (int ni = 1; ni < 8; ++ni) mx = fmaxf(mx, v[ni]);
#pragma unroll
    for (int sh = 1; sh < 16; sh <<= 1) mx = fmaxf(mx, __shfl_xor(mx, sh, 16));
    float sm = 0.f;
#pragma unroll
    for (int ni = 0; ni < 8; ++ni) sm += __expf(v[ni] - mx);
#pragma unroll
    for (int sh = 1; sh < 16; sh <<= 1) sm += __shfl_xor(sm, sh, 16);
    const float lse = mx + __logf(sm);
    float cand = 0.f;
#pragma unroll
    for (int ni = 0; ni < 8; ++ni)
      if (ni == tj) cand = v[ni];                // positive-pair tile (uniform)
    const float vp = __shfl(cand, rloc, 16);
    lacc += vp - lse;                            // x16 lanes per row
  }
#pragma unroll
  for (int sh = 1; sh < 64; sh <<= 1) lacc += __shfl_xor(lacc, sh, 64);
  if (lane == 0) wred[w] = lacc;
  __syncthreads();
  if (t == 0) {
    float tot = 0.f;
#pragma unroll
    for (int i = 0; i < 8; ++i) tot += wred[i];
    // tot = 16 * sum_rows(pos) for this hw; spread-atomic into 64 slots
    atomicAdd(&g_acc[(hw & 63) * 16], tot);
  }
}

// ---------------------------------------------------------------------------
// Kernel 3: final reduce of the 64 partial slots -> out[0].
// loss = -sum / (HW * 2B) with the x16 lane duplication (2097152 = 1024*128*16)
// ---------------------------------------------------------------------------
__global__ __launch_bounds__(64) void k_reduce(float* __restrict__ out) {
  const int t = threadIdx.x;
  float v = g_acc[t * 16];
#pragma unroll
  for (int sh = 1; sh < 64; sh <<= 1) v += __shfl_xor(v, sh, 64);
  if (t == 0) out[0] = -v * (1.0f / 2097152.0f);
}

extern "C" void kernel_launch(void* const* d_in, const int* in_sizes, int n_in,
                              void* d_out, int out_size, void* d_ws, size_t ws_size,
                              hipStream_t stream) {
  const float* inp = (const float*)d_in[0];
  const float* tgt = (const float*)d_in[1];
  unsigned char* wsF = (unsigned char*)d_ws;
  k_transpose<<<dim3(128, 4), 512, 0, stream>>>(inp, tgt, wsF);
  k_gram<<<dim3(HWPOS), 512, 0, stream>>>(wsF);
  k_reduce<<<1, 64, 0, stream>>>((float*)d_out);
}

// Round 9
// 173.160 us; speedup vs baseline: 1.0300x; 1.0300x over previous
//
#include <hip/hip_runtime.h>
#include <stdint.h>

#define HWPOS 1024
#define CCH   256
#define RROWS 128   // 2B
#define EPSF  1.1920928955078125e-07f

typedef __attribute__((ext_vector_type(4))) float float4v;

// 64 partial-sum slots (64B padded) for gram's spread atomics; zeroed by
// k_transpose block (0,0,0) (stream order + kernel boundary => race-free).
__device__ float g_acc[64 * 16];

__device__ __forceinline__ uint32_t pk4_fp8(float a, float b, float c, float d) {
  int v = 0;
  v = __builtin_amdgcn_cvt_pk_fp8_f32(a, b, v, false);  // bytes 0,1
  v = __builtin_amdgcn_cvt_pk_fp8_f32(c, d, v, true);   // bytes 2,3
  return (uint32_t)v;
}

// ws layout v15 (fp8), UNSWIZZLED LINEAR: addr(r,hw,dd) = r*262144 + hw*256
// + dd*16  (dd = c-chunk of 16). The gram LDS swizzle s = dd ^ (r&15) is now
// applied in k_gram's staging SOURCE address (per-lane-free), not baked into
// ws -> transpose output is fully linear/dense.
//
// Round-8 lesson: v14 read dense but wrote 16B per 64B line (block-uniform
// slot) -> WRITE_SIZE doubled to 66MB (partial-line RMW). v15 makes BOTH
// sides dense: reads = 2KB contiguous segments; each thread writes its hw's
// 64B line completely (4 consecutive 16B stores).

// ---------------------------------------------------------------------------
// Kernel 1 (v15, fp8): transpose [B,C,H,W] f32 -> ws fp8-e4m3.
// Block = (r, cq 0..3, hwh 0..1): 64 c x 512 hw, 256 threads, 32KB LDS,
// 4 blocks/CU (inter-block overlap hides barrier-serialized staging).
// Per sub-tile dl (16 c x 512 hw = 32KB f32):
//   stage via global_load_lds (register-free; src 1KB contiguous per instr,
//   dest lane-linear) -> T[c][hw]; column-read (stride 4B = 2 lanes/bank,
//   free) -> cvt -> accumulate uint4 a[dl] in regs (static indexing).
// End: thread writes 2 hw x 64B fully-dense lines (4 consecutive uint4).
// Grid (128, 4, 2) = 1024 blocks.
// ---------------------------------------------------------------------------
__global__ __launch_bounds__(256, 4) void k_transpose(const float* __restrict__ inp,
                                                      const float* __restrict__ tgt,
                                                      unsigned char* __restrict__ wsF) {
  __shared__ float T[16 * 512];     // 32 KB: [c_l 0..15][hw_l 0..511]
  const int t    = threadIdx.x;
  const int r    = blockIdx.x;      // row 0..127
  const int cq   = blockIdx.y;      // c-quarter (64 c)
  const int hwh  = blockIdx.z;      // hw half (512 hw)
  if (r == 0 && cq == 0 && hwh == 0 && t < 64) g_acc[t * 16] = 0.0f;
  const float* src = (r < 64) ? (inp + (size_t)r * CCH * HWPOS)
                              : (tgt + (size_t)(r - 64) * CCH * HWPOS);
  const int lane = t & 63;
  const int wv   = t >> 6;          // 4 waves
  uint4 a0[4], a1[4];
#pragma unroll
  for (int dl = 0; dl < 4; ++dl) {
    const int c0 = cq * 64 + dl * 16;       // 16 c-rows this sub-tile
    // stage 32KB: wave wv loads rows {4wv..4wv+3}, 2 x 1KB segments each
#pragma unroll
    for (int j = 0; j < 8; ++j) {
      const int row = wv * 4 + (j >> 1);    // 0..15
      const int seg = j & 1;                // 1KB segment within 2KB half-row
      const float* gp = src + (size_t)(c0 + row) * HWPOS
                      + hwh * 512 + seg * 256 + lane * 4;
      __builtin_amdgcn_global_load_lds(
          (const __attribute__((address_space(1))) unsigned int*)gp,
          (__attribute__((address_space(3))) unsigned int*)
              ((unsigned char*)T + row * 2048 + seg * 1024 + lane * 16),
          16, 0, 0);
    }
    __syncthreads();
    // column read + cvt for 2 hw per thread (static reg indexing)
    float x0[16], x1[16];
#pragma unroll
    for (int c = 0; c < 16; ++c) { x0[c] = T[c * 512 + t];
                                   x1[c] = T[c * 512 + t + 256]; }
    uint4 o0, o1;
    o0.x = pk4_fp8(x0[0],  x0[1],  x0[2],  x0[3]);
    o0.y = pk4_fp8(x0[4],  x0[5],  x0[6],  x0[7]);
    o0.z = pk4_fp8(x0[8],  x0[9],  x0[10], x0[11]);
    o0.w = pk4_fp8(x0[12], x0[13], x0[14], x0[15]);
    o1.x = pk4_fp8(x1[0],  x1[1],  x1[2],  x1[3]);
    o1.y = pk4_fp8(x1[4],  x1[5],  x1[6],  x1[7]);
    o1.z = pk4_fp8(x1[8],  x1[9],  x1[10], x1[11]);
    o1.w = pk4_fp8(x1[12], x1[13], x1[14], x1[15]);
#pragma unroll
    for (int d2 = 0; d2 < 4; ++d2) {
      if (d2 == dl) { a0[d2] = o0; a1[d2] = o1; }
    }
    if (dl < 3) __syncthreads();    // protect T before next stage overwrites
  }
  // write: per hw one FULL 64B line (4 consecutive 16B stores)
  unsigned char* w0 = wsF + (size_t)r * 262144
                    + (size_t)(hwh * 512 + t) * 256 + cq * 64;
  unsigned char* w1 = w0 + (size_t)256 * 256;   // hw + 256
#pragma unroll
  for (int dl = 0; dl < 4; ++dl) {
    *(uint4*)(w0 + dl * 16) = a0[dl];
    *(uint4*)(w1 + dl * 16) = a1[dl];
  }
}

// ---------------------------------------------------------------------------
// Kernel 2 (v9, fp8): one block per hw; whole 32KB fp8 image in one LDS
// buffer; 8 waves x mfma_f32_16x16x32_fp8_fp8; fused masked log-softmax +
// positive-pair extraction; spread atomics into g_acc. v9 change: ws is now
// linear [r][hw][dd]; the s = dd^(r&15) swizzle is applied HERE in the
// staging source (dd = ss ^ (rr&15)) -> Fs contents byte-identical to every
// prior version; MFMA/softmax algebra untouched. Per wave the 16 chunks of
// a 256B row are the same bytes, XOR-permuted in 16B units (coalescer is
// order-independent within the granule set).
// ---------------------------------------------------------------------------
__global__ __launch_bounds__(512, 4) void k_gram(const unsigned char* __restrict__ wsF) {
  __shared__ unsigned char Fs[32768];   // full fp8 image, swizzled
  __shared__ float sInv[RROWS];
  __shared__ float wred[8];
  const int t  = threadIdx.x;
  const int hw = blockIdx.x;
  const int lane = t & 63;
  const int w    = t >> 6;        // wave id 0..7 = row-tile
  const int lid  = lane & 15;
  const int quad = lane >> 4;
  float4v acc[8];
#pragma unroll
  for (int ni = 0; ni < 8; ++ni) acc[ni] = (float4v){0.f, 0.f, 0.f, 0.f};
#pragma unroll
  for (int it = 0; it < 4; ++it) {
    const int ch = it * 512 + t;                    // Fs chunk index 0..2047
    const int rr = ch >> 4;                         // r page
    const int ss = ch & 15;                         // Fs slot within row
    const int dd = ss ^ (rr & 15);                  // source data chunk
    const size_t goff = (size_t)rr * 262144 + (size_t)hw * 256
                      + (size_t)dd * 16;
    __builtin_amdgcn_global_load_lds(
        (const __attribute__((address_space(1))) unsigned int*)(wsF + goff),
        (__attribute__((address_space(3))) unsigned int*)(Fs + (size_t)ch * 16),
        16, 0, 0);
  }
  __syncthreads();
  const int rowA = (w << 4) | lid;
#pragma unroll
  for (int ks = 0; ks < 8; ++ks) {
    const int d    = 2 * ks + (quad >> 1);      // data chunk for this frag
    const int off  = ((d ^ lid) << 4) + (quad & 1) * 8;  // swizzled byte off
    long a = *(const long*)&Fs[rowA * 256 + off];
#pragma unroll
    for (int ni = 0; ni < 8; ++ni) {
      long b = *(const long*)&Fs[(((ni << 4) | lid)) * 256 + off];
      acc[ni] = __builtin_amdgcn_mfma_f32_16x16x32_fp8_fp8(a, b, acc[ni], 0, 0, 0);
    }
  }
  // diagonal extract (no dynamic indexing): tile w (uniform), elem lid&3
  {
    float diagv = 0.f;
#pragma unroll
    for (int ni = 0; ni < 8; ++ni) {
      if (ni == w) {
#pragma unroll
        for (int e = 0; e < 4; ++e)
          if (e == (lid & 3)) diagv = acc[ni][e];
      }
    }
    if ((lid >> 2) == quad) {
      sInv[(w << 4) | lid] = 1.0f / fmaxf(sqrtf(diagv), EPSF);
    }
  }
  __syncthreads();
  float invj[8];
#pragma unroll
  for (int ni = 0; ni < 8; ++ni) invj[ni] = sInv[(ni << 4) | lid];
  const int tj = (w + 4) & 7;     // partner col-tile (wave-uniform)
  float lacc = 0.f;
#pragma unroll
  for (int reg = 0; reg < 4; ++reg) {
    const int rloc = quad * 4 + reg;           // local row in tile
    const int rg   = (w << 4) | rloc;          // global row 0..127
    const float invi = sInv[rg];
    float v[8];
#pragma unroll
    for (int ni = 0; ni < 8; ++ni) v[ni] = 2.0f * acc[ni][reg] * invi * invj[ni];
#pragma unroll
    for (int ni = 0; ni < 8; ++ni)
      if (ni == w && lid == rloc) v[ni] = -3.0e38f;   // mask diagonal
    float mx = v[0];
#pragma unroll
    for (int ni = 1; ni < 8; ++ni) mx = fmaxf(mx, v[ni]);
#pragma unroll
    for (int sh = 1; sh < 16; sh <<= 1) mx = fmaxf(mx, __shfl_xor(mx, sh, 16));
    float sm = 0.f;
#pragma unroll
    for (int ni = 0; ni < 8; ++ni) sm += __expf(v[ni] - mx);
#pragma unroll
    for (int sh = 1; sh < 16; sh <<= 1) sm += __shfl_xor(sm, sh, 16);
    const float lse = mx + __logf(sm);
    float cand = 0.f;
#pragma unroll
    for (int ni = 0; ni < 8; ++ni)
      if (ni == tj) cand = v[ni];                // positive-pair tile (uniform)
    const float vp = __shfl(cand, rloc, 16);
    lacc += vp - lse;                            // x16 lanes per row
  }
#pragma unroll
  for (int sh = 1; sh < 64; sh <<= 1) lacc += __shfl_xor(lacc, sh, 64);
  if (lane == 0) wred[w] = lacc;
  __syncthreads();
  if (t == 0) {
    float tot = 0.f;
#pragma unroll
    for (int i = 0; i < 8; ++i) tot += wred[i];
    // tot = 16 * sum_rows(pos) for this hw; spread-atomic into 64 slots
    atomicAdd(&g_acc[(hw & 63) * 16], tot);
  }
}

// ---------------------------------------------------------------------------
// Kernel 3: final reduce of the 64 partial slots -> out[0].
// loss = -sum / (HW * 2B) with the x16 lane duplication (2097152 = 1024*128*16)
// ---------------------------------------------------------------------------
__global__ __launch_bounds__(64) void k_reduce(float* __restrict__ out) {
  const int t = threadIdx.x;
  float v = g_acc[t * 16];
#pragma unroll
  for (int sh = 1; sh < 64; sh <<= 1) v += __shfl_xor(v, sh, 64);
  if (t == 0) out[0] = -v * (1.0f / 2097152.0f);
}

extern "C" void kernel_launch(void* const* d_in, const int* in_sizes, int n_in,
                              void* d_out, int out_size, void* d_ws, size_t ws_size,
                              hipStream_t stream) {
  const float* inp = (const float*)d_in[0];
  const float* tgt = (const float*)d_in[1];
  unsigned char* wsF = (unsigned char*)d_ws;
  k_transpose<<<dim3(128, 4, 2), 256, 0, stream>>>(inp, tgt, wsF);
  k_gram<<<dim3(HWPOS), 512, 0, stream>>>(wsF);
  k_reduce<<<1, 64, 0, stream>>>((float*)d_out);
}